// Round 1
// baseline (127.075 us; speedup 1.0000x reference)
//
#include <hip/hip_runtime.h>

// SRM block fused kernel for M=4, S=2, B=2, C=128, H=W=512.
//
// Key derivation: the restore index map is an involution (pair-swap
// permutation), and per window (P,Q) the 16 source coordinates of the
// rearrange step equal the 16 destination coordinates of the restore step,
// slot-for-slot. So the entire op is:
//   per (b,c,P,Q): gather 4x4 pixels at rows{4P-2,4P-1,4P+4,4P+5} x
//   cols{4Q-2,4Q-1,4Q+4,4Q+5} (clamped at edges), apply out = fc_w*v + fc_b
//   (16x16), write results back to the SAME coordinates in the output.

#define HDIM 512
#define WDIM 512
#define NPB  128   // windows per dim (512/4)

__global__ __launch_bounds__(256) void srm_fused_kernel(
    const float* __restrict__ x, const float* __restrict__ fw,
    const float* __restrict__ fb, float* __restrict__ out)
{
    __shared__ float sw[16][16];
    __shared__ float sb[16];
    const int tid = threadIdx.x;
    sw[tid >> 4][tid & 15] = fw[tid];       // 256 weights
    if (tid < 16) sb[tid] = fb[tid];
    __syncthreads();

    const int wid = blockIdx.x * 256 + tid;   // global window id
    const int Q  = wid & 127;
    const int P  = (wid >> 7) & 127;
    const int bc = wid >> 14;                 // b*C + c in [0,256)

    const int r0 = (P == 0)   ? 0   : 4 * P - 2;
    const int r2 = (P == 127) ? 510 : 4 * P + 4;
    const int c0 = (Q == 0)   ? 0   : 4 * Q - 2;
    const int c2 = (Q == 127) ? 510 : 4 * Q + 4;

    const float* xp = x   + (size_t)bc * (HDIM * WDIM);
    float*       op = out + (size_t)bc * (HDIM * WDIM);

    const int rows[4] = {r0, r0 + 1, r2, r2 + 1};

    float v[16];
    #pragma unroll
    for (int r = 0; r < 4; ++r) {
        const float* rowp = xp + rows[r] * WDIM;
        const float2 a = *reinterpret_cast<const float2*>(rowp + c0);
        const float2 b = *reinterpret_cast<const float2*>(rowp + c2);
        v[r * 4 + 0] = a.x; v[r * 4 + 1] = a.y;
        v[r * 4 + 2] = b.x; v[r * 4 + 3] = b.y;
    }

    float u[16];
    #pragma unroll
    for (int o = 0; o < 16; ++o) {
        float acc = sb[o];
        #pragma unroll
        for (int f = 0; f < 16; ++f) acc += sw[o][f] * v[f];
        u[o] = acc;
    }

    #pragma unroll
    for (int r = 0; r < 4; ++r) {
        float* rowp = op + rows[r] * WDIM;
        *reinterpret_cast<float2*>(rowp + c0) = make_float2(u[r * 4 + 0], u[r * 4 + 1]);
        *reinterpret_cast<float2*>(rowp + c2) = make_float2(u[r * 4 + 2], u[r * 4 + 3]);
    }
}

extern "C" void kernel_launch(void* const* d_in, const int* in_sizes, int n_in,
                              void* d_out, int out_size, void* d_ws, size_t ws_size,
                              hipStream_t stream) {
    const float* x  = (const float*)d_in[0];
    const float* fw = (const float*)d_in[1];
    const float* fb = (const float*)d_in[2];
    float* out = (float*)d_out;

    // total windows = B*C * 128 * 128 = 2*128*128*128 = 4,194,304
    const int total_windows = 2 * 128 * NPB * NPB;
    const int blocks = total_windows / 256;   // 16384
    srm_fused_kernel<<<blocks, 256, 0, stream>>>(x, fw, fb, out);
}